// Round 1
// baseline (96.600 us; speedup 1.0000x reference)
//
#include <hip/hip_runtime.h>
#include <math.h>

// Problem constants: x = (8, 3, 1024, 1024) f32, out = (8, 3, 1024, 1024) f32
constexpr int H = 1024, W = 1024, B = 8;
constexpr int NPIX = H * W;                 // 1,048,576
constexpr int TH = 16, TW = 128;            // stencil tile per 256-thread block
constexpr int LSTR = 136;                   // LDS row stride (floats); interior at col 4 (16B aligned)

// Stage 1: grayscale + 8-neighbor weighted stencil (zero pad), write un-normalized
// t into channel-0 slots of out; accumulate per-image sum / sumsq via double atomics.
__global__ __launch_bounds__(256)
void ltpe_stage1(const float* __restrict__ x, float* __restrict__ out,
                 double* __restrict__ acc)
{
    __shared__ float gt[(TH + 2) * LSTR];
    const int tid  = threadIdx.x;
    const int b    = blockIdx.z;
    const int row0 = blockIdx.y * TH;
    const int col0 = blockIdx.x * TW;
    const float* xb = x + (size_t)b * 3 * NPIX;

    // Interior staging: 18 rows x 32 float4 (cols col0 .. col0+127), row-bounds only.
    for (int v = tid; v < (TH + 2) * (TW / 4); v += 256) {
        const int r  = v >> 5;              // TW/4 == 32
        const int c4 = v & 31;
        const int gi = row0 - 1 + r;
        float4 g4 = make_float4(0.f, 0.f, 0.f, 0.f);
        if ((unsigned)gi < (unsigned)H) {
            const float* p = xb + (size_t)gi * W + col0 + c4 * 4;
            const float4 r0 = *reinterpret_cast<const float4*>(p);
            const float4 r1 = *reinterpret_cast<const float4*>(p + NPIX);
            const float4 r2 = *reinterpret_cast<const float4*>(p + 2 * NPIX);
            g4.x = 0.3f * r0.x + 0.59f * r1.x + 0.11f * r2.x;
            g4.y = 0.3f * r0.y + 0.59f * r1.y + 0.11f * r2.y;
            g4.z = 0.3f * r0.z + 0.59f * r1.z + 0.11f * r2.z;
            g4.w = 0.3f * r0.w + 0.59f * r1.w + 0.11f * r2.w;
        }
        *reinterpret_cast<float4*>(&gt[r * LSTR + 4 + c4 * 4]) = g4;  // 16B aligned
    }
    // Halo columns (lc = -1 and 128): 36 scalar elements.
    for (int v = tid; v < (TH + 2) * 2; v += 256) {
        const int r  = v >> 1;
        const int lc = (v & 1) ? TW : -1;
        const int gi = row0 - 1 + r;
        const int gj = col0 + lc;
        float g = 0.f;
        if ((unsigned)gi < (unsigned)H && (unsigned)gj < (unsigned)W) {
            const float* p = xb + (size_t)gi * W + gj;
            g = 0.3f * p[0] + 0.59f * p[NPIX] + 0.11f * p[2 * NPIX];
        }
        gt[r * LSTR + 4 + lc] = g;
    }
    __syncthreads();

    // Compute phase: 256 threads = 128 cols x 2 row-halves, 8 rows each.
    // OFFSETS j: (0,-1) (1,-1) (1,0) (1,1) (0,1) (-1,1) (-1,0) (-1,-1), w_j = 2^j/255.
    // sum_j w_j == 1 exactly  =>  t = 0.5*(g+1) - 0.5 * sum_j w_j * nb_j
    constexpr float w0 = 1.f / 255.f,  w1 = 2.f / 255.f,  w2 = 4.f / 255.f,
                    w3 = 8.f / 255.f,  w4 = 16.f / 255.f, w5 = 32.f / 255.f,
                    w6 = 64.f / 255.f, w7 = 128.f / 255.f;
    const int c  = tid & (TW - 1);
    const int rh = tid >> 7;
    float ls = 0.f, lss = 0.f;
    float* ocol = out + (size_t)b * 3 * NPIX + (size_t)row0 * W + col0 + c;
    #pragma unroll
    for (int rr = 0; rr < TH / 2; ++rr) {
        const int r = rr * 2 + rh;
        const float* up  = &gt[(r + 0) * LSTR + 4 + c];
        const float* mid = &gt[(r + 1) * LSTR + 4 + c];
        const float* dn  = &gt[(r + 2) * LSTR + 4 + c];
        const float g = mid[0];
        float s;
        s = w0 * mid[-1];
        s = fmaf(w1, dn[-1], s);
        s = fmaf(w2, dn[0],  s);
        s = fmaf(w3, dn[1],  s);
        s = fmaf(w4, mid[1], s);
        s = fmaf(w5, up[1],  s);
        s = fmaf(w6, up[0],  s);
        s = fmaf(w7, up[-1], s);
        const float t = 0.5f * g + 0.5f - 0.5f * s;
        ocol[(size_t)r * W] = t;
        ls += t;
        lss = fmaf(t, t, lss);
    }

    // Block reduction: wave64 shuffle -> LDS -> thread 0 -> double atomics.
    #pragma unroll
    for (int off = 32; off >= 1; off >>= 1) {
        ls  += __shfl_down(ls, off);
        lss += __shfl_down(lss, off);
    }
    __shared__ float red[8];
    const int wv = tid >> 6;
    if ((tid & 63) == 0) { red[wv] = ls; red[4 + wv] = lss; }
    __syncthreads();
    if (tid == 0) {
        const float bs  = red[0] + red[1] + red[2] + red[3];
        const float bss = red[4] + red[5] + red[6] + red[7];
        atomicAdd(&acc[b], (double)bs);
        atomicAdd(&acc[8 + b], (double)bss);
    }
}

// Stage 2: finalize per-image mean and rstd (8 threads).
__global__ void ltpe_stage2(const double* __restrict__ acc, float* __restrict__ scal)
{
    const int b = threadIdx.x;
    if (b < B) {
        const double n    = (double)NPIX;
        const double mean = acc[b] / n;
        const double var  = acc[8 + b] / n - mean * mean;
        scal[2 * b]     = (float)mean;
        scal[2 * b + 1] = (float)(1.0 / sqrt(var + 1e-5));
    }
}

// Stage 3: normalize channel-0 t in place and replicate to channels 1,2 (float4).
__global__ __launch_bounds__(256)
void ltpe_stage3(float* __restrict__ out, const float* __restrict__ scal)
{
    const int b = blockIdx.y;
    const float mean = scal[2 * b];
    const float rstd = scal[2 * b + 1];
    const size_t base = (size_t)b * 3 * NPIX +
                        ((size_t)blockIdx.x * 256 + threadIdx.x) * 4;
    const float4 t4 = *reinterpret_cast<const float4*>(out + base);
    float4 y;
    y.x = (t4.x - mean) * rstd;
    y.y = (t4.y - mean) * rstd;
    y.z = (t4.z - mean) * rstd;
    y.w = (t4.w - mean) * rstd;
    *reinterpret_cast<float4*>(out + base)            = y;
    *reinterpret_cast<float4*>(out + base + NPIX)     = y;
    *reinterpret_cast<float4*>(out + base + 2 * NPIX) = y;
}

extern "C" void kernel_launch(void* const* d_in, const int* in_sizes, int n_in,
                              void* d_out, int out_size, void* d_ws, size_t ws_size,
                              hipStream_t stream)
{
    const float* x = (const float*)d_in[0];
    float* out = (float*)d_out;
    double* acc = (double*)d_ws;                       // 16 doubles: sum[8], sumsq[8]
    float* scal = (float*)((char*)d_ws + 128);         // 16 floats: mean/rstd pairs

    hipMemsetAsync(d_ws, 0, 128, stream);              // zero accumulators each call
    ltpe_stage1<<<dim3(W / TW, H / TH, B), 256, 0, stream>>>(x, out, acc);
    ltpe_stage2<<<1, 64, 0, stream>>>(acc, scal);
    ltpe_stage3<<<dim3(NPIX / 1024, B), 256, 0, stream>>>(out, scal);
}

// Round 2
// 55.934 us; speedup vs baseline: 1.7270x; 1.7270x over previous
//
#include <hip/hip_runtime.h>
#include <math.h>

// x = (8, 3, 1024, 1024) f32, out = (8, 3, 1024, 1024) f32
constexpr int H = 1024, W = 1024, B = 8;
constexpr int NPIX = H * W;

__device__ __forceinline__ float grayat(const float* __restrict__ xb, int r, int c) {
    const float* p = xb + (size_t)r * W + c;
    return 0.3f * p[0] + 0.59f * p[NPIX] + 0.11f * p[2 * NPIX];
}

// Stage 1: one block = one row of one image (256 threads x 4 cols).
// Each thread: 9 independent float4 loads (3 rows x 3 channels) -> 3 gray quads,
// horizontal neighbors via wave shuffle, 3x3 weighted stencil, write un-normalized
// t to channel-0 of out, block-reduce sum/sumsq -> per-block fp32 partial (no atomics).
__global__ __launch_bounds__(256)
void ltpe_stage1(const float* __restrict__ x, float* __restrict__ out,
                 float2* __restrict__ part)
{
    const int b    = blockIdx.y;
    const int k    = blockIdx.x;                  // dispatch row index
    const int r    = ((k & 7) << 7) | (k >> 3);   // XCD-chunked bijective swizzle (8 x 128)
    const int tid  = threadIdx.x;
    const int c    = tid << 2;                    // first output column
    const int lane = tid & 63;

    const float* xb = x + (size_t)b * 3 * NPIX;

    // 3 rows x 3 channels, all loads independent.
    float4 g[3];
    #pragma unroll
    for (int dr = 0; dr < 3; ++dr) {
        const int rr = r + dr - 1;
        float4 q0 = {0.f,0.f,0.f,0.f}, q1 = q0, q2 = q0;
        if ((unsigned)rr < (unsigned)H) {
            const float* p = xb + (size_t)rr * W + c;
            q0 = *reinterpret_cast<const float4*>(p);
            q1 = *reinterpret_cast<const float4*>(p + NPIX);
            q2 = *reinterpret_cast<const float4*>(p + 2 * NPIX);
        }
        g[dr].x = 0.3f * q0.x + 0.59f * q1.x + 0.11f * q2.x;
        g[dr].y = 0.3f * q0.y + 0.59f * q1.y + 0.11f * q2.y;
        g[dr].z = 0.3f * q0.z + 0.59f * q1.z + 0.11f * q2.z;
        g[dr].w = 0.3f * q0.w + 0.59f * q1.w + 0.11f * q2.w;
    }

    // Horizontal neighbors from adjacent lanes; wave-edge lanes patch via scalar loads.
    float gl[3], gr[3];
    #pragma unroll
    for (int dr = 0; dr < 3; ++dr) {
        gl[dr] = __shfl_up(g[dr].w, 1);
        gr[dr] = __shfl_down(g[dr].x, 1);
    }
    if (lane == 0) {
        #pragma unroll
        for (int dr = 0; dr < 3; ++dr) {
            const int rr = r + dr - 1;
            gl[dr] = (c > 0 && (unsigned)rr < (unsigned)H) ? grayat(xb, rr, c - 1) : 0.f;
        }
    }
    if (lane == 63) {
        #pragma unroll
        for (int dr = 0; dr < 3; ++dr) {
            const int rr = r + dr - 1;
            gr[dr] = (c + 4 < W && (unsigned)rr < (unsigned)H) ? grayat(xb, rr, c + 4) : 0.f;
        }
    }

    // 6-wide gray rows: index 0 is col c-1, 1..4 are c..c+3, 5 is c+4.
    float up[6], mi[6], dn[6];
    up[0]=gl[0]; up[1]=g[0].x; up[2]=g[0].y; up[3]=g[0].z; up[4]=g[0].w; up[5]=gr[0];
    mi[0]=gl[1]; mi[1]=g[1].x; mi[2]=g[1].y; mi[3]=g[1].z; mi[4]=g[1].w; mi[5]=gr[1];
    dn[0]=gl[2]; dn[1]=g[2].x; dn[2]=g[2].y; dn[3]=g[2].z; dn[4]=g[2].w; dn[5]=gr[2];

    // OFFSETS j: (0,-1)(1,-1)(1,0)(1,1)(0,1)(-1,1)(-1,0)(-1,-1), w_j = 2^j/255, sum w == 1
    // => t = 0.5*(g+1) - 0.5 * sum_j w_j * nb_j
    constexpr float w0 = 1.f/255.f,  w1 = 2.f/255.f,  w2 = 4.f/255.f,  w3 = 8.f/255.f,
                    w4 = 16.f/255.f, w5 = 32.f/255.f, w6 = 64.f/255.f, w7 = 128.f/255.f;
    float tv[4];
    #pragma unroll
    for (int kk = 0; kk < 4; ++kk) {
        float s = w0 * mi[kk];              // mid[-1]
        s = fmaf(w1, dn[kk],     s);        // dn[-1]
        s = fmaf(w2, dn[kk + 1], s);        // dn[0]
        s = fmaf(w3, dn[kk + 2], s);        // dn[+1]
        s = fmaf(w4, mi[kk + 2], s);        // mid[+1]
        s = fmaf(w5, up[kk + 2], s);        // up[+1]
        s = fmaf(w6, up[kk + 1], s);        // up[0]
        s = fmaf(w7, up[kk],     s);        // up[-1]
        tv[kk] = 0.5f * mi[kk + 1] + 0.5f - 0.5f * s;
    }

    float4 t4 = {tv[0], tv[1], tv[2], tv[3]};
    *reinterpret_cast<float4*>(out + (size_t)b * 3 * NPIX + (size_t)r * W + c) = t4;

    // Block reduction: wave shuffle -> LDS -> one fp32 partial pair per block.
    float s  = tv[0] + tv[1] + tv[2] + tv[3];
    float ss = tv[0]*tv[0] + tv[1]*tv[1] + tv[2]*tv[2] + tv[3]*tv[3];
    #pragma unroll
    for (int off = 32; off >= 1; off >>= 1) {
        s  += __shfl_down(s, off);
        ss += __shfl_down(ss, off);
    }
    __shared__ float2 wred[4];
    if (lane == 0) wred[tid >> 6] = make_float2(s, ss);
    __syncthreads();
    if (tid == 0) {
        float2 a0 = wred[0], a1 = wred[1], a2 = wred[2], a3 = wred[3];
        part[(size_t)b * H + k] = make_float2(a0.x + a1.x + a2.x + a3.x,
                                              a0.y + a1.y + a2.y + a3.y);
    }
}

// Stage 2: per-image reduce of 1024 fp32 partials in double -> mean, rstd.
__global__ __launch_bounds__(256)
void ltpe_stage2(const float2* __restrict__ part, float* __restrict__ scal)
{
    const int b = blockIdx.x;
    const int tid = threadIdx.x;
    double s = 0.0, ss = 0.0;
    #pragma unroll
    for (int i = 0; i < 4; ++i) {
        float2 p = part[(size_t)b * H + tid + i * 256];
        s += (double)p.x; ss += (double)p.y;
    }
    #pragma unroll
    for (int off = 32; off >= 1; off >>= 1) {
        s  += __shfl_down(s, off);
        ss += __shfl_down(ss, off);
    }
    __shared__ double red[8];
    const int lane = tid & 63, wv = tid >> 6;
    if (lane == 0) { red[wv] = s; red[4 + wv] = ss; }
    __syncthreads();
    if (tid == 0) {
        const double S  = red[0] + red[1] + red[2] + red[3];
        const double SS = red[4] + red[5] + red[6] + red[7];
        const double n    = (double)NPIX;
        const double mean = S / n;
        const double var  = SS / n - mean * mean;
        scal[2 * b]     = (float)mean;
        scal[2 * b + 1] = (float)(1.0 / sqrt(var + 1e-5));
    }
}

// Stage 3: normalize channel-0 t in place and replicate to channels 1,2 (float4).
__global__ __launch_bounds__(256)
void ltpe_stage3(float* __restrict__ out, const float* __restrict__ scal)
{
    const int b = blockIdx.y;
    const float mean = scal[2 * b];
    const float rstd = scal[2 * b + 1];
    const size_t base = (size_t)b * 3 * NPIX +
                        ((size_t)blockIdx.x * 256 + threadIdx.x) * 4;
    const float4 t4 = *reinterpret_cast<const float4*>(out + base);
    float4 y;
    y.x = (t4.x - mean) * rstd;
    y.y = (t4.y - mean) * rstd;
    y.z = (t4.z - mean) * rstd;
    y.w = (t4.w - mean) * rstd;
    *reinterpret_cast<float4*>(out + base)            = y;
    *reinterpret_cast<float4*>(out + base + NPIX)     = y;
    *reinterpret_cast<float4*>(out + base + 2 * NPIX) = y;
}

extern "C" void kernel_launch(void* const* d_in, const int* in_sizes, int n_in,
                              void* d_out, int out_size, void* d_ws, size_t ws_size,
                              hipStream_t stream)
{
    const float* x = (const float*)d_in[0];
    float* out = (float*)d_out;
    float2* part = (float2*)d_ws;                       // 8192 float2 = 64 KiB
    float* scal  = (float*)((char*)d_ws + 65536);       // 16 floats: mean/rstd pairs

    ltpe_stage1<<<dim3(H, B), 256, 0, stream>>>(x, out, part);
    ltpe_stage2<<<B, 256, 0, stream>>>(part, scal);
    ltpe_stage3<<<dim3(NPIX / 1024, B), 256, 0, stream>>>(out, scal);
}